// Round 4
// baseline (180.330 us; speedup 1.0000x reference)
//
#include <hip/hip_runtime.h>

// DispNetC correlation volume: out[b,d,h,w] = mean_c L[b,c,h,w]*R[b,c,h,w-d]
// for w>=d, else 0.  Inputs f32, output f32 (both proven: R1 NaN forensics for
// inputs; R2/R3 bit-identical absmax for output interpretation).
// Pure-VALU register-blocked design: ~2.4 GFLOP vs a 145 MB stream ->
// memory-bound; MFMA unnecessary.
//
// One block per (b,h). 320 threads = 10 d-tiles x 32 w-tiles of 4x4 outputs.
// Per 32-channel LDS chunk, each active thread does per channel:
//   1x ds_read_b128 (L[w0..w0+3]) + 2x ds_read_b128 (R window, left-pad 4)
//   + 16x v_fmac_f32, with all window picks static (wi-di in [-3,3]).

#define NB 8
#define NC 256
#define NH 64
#define NWD 128
#define ND 40
#define KC 32
#define RST 132  // R row stride in LDS: 4 left-pad + 128 (x4B = 528 B, 16B-mult)

__global__ __launch_bounds__(320) void corr_valu(
    const float* __restrict__ Lg,
    const float* __restrict__ Rg,
    float* __restrict__ out)
{
  __shared__ __align__(16) float Ls[KC * NWD];  // 16 KB
  __shared__ __align__(16) float Rs[KC * RST];  // 16.5 KB

  const int blk = blockIdx.x;
  const int b   = blk >> 6;     // NH = 64
  const int h   = blk & 63;
  const int tid = threadIdx.x;
  const int dt  = tid >> 5;     // 0..9
  const int wt  = tid & 31;     // 0..31
  const int d0  = dt << 2;      // 0..36
  const int w0  = wt << 2;      // 0..124
  const bool active = (w0 >= d0);  // tiles fully left of the band do no math

  // Zero the w < d triangle (d_out is poisoned before each timed launch).
  for (int t = tid; t < ND * ND; t += 320) {
    const int d = t / ND;
    const int w = t - d * ND;
    if (w < d)
      out[(((size_t)b * ND + d) * NH + h) * NWD + w] = 0.0f;
  }

  float acc[4][4] = {{0.f}};

  const size_t HW   = (size_t)NH * NWD;
  const size_t base = (size_t)b * NC * HW + (size_t)h * NWD;
  const int    X0   = w0 - d0;  // >= 0 for active threads, multiple of 4

  for (int kc = 0; kc < NC; kc += KC) {
    __syncthreads();  // previous chunk's compute done reading LDS
    // ---- stage KC channels of L and R (f32, coalesced float4) ----
    for (int idx = tid; idx < 2 * KC * 32; idx += 320) {
      const int which = (idx >= KC * 32);            // 0 = L, 1 = R
      const int r     = (idx & (KC * 32 - 1)) >> 5;  // channel row 0..KC-1
      const int col   = (idx & 31) << 2;             // w offset 0..124
      const float* src = which ? Rg : Lg;
      const float4 v = *(const float4*)(src + base + (size_t)(kc + r) * HW + col);
      if (which) *(float4*)(&Rs[r * RST + 4 + col]) = v;  // pad[0..3] stays garbage
      else       *(float4*)(&Ls[r * NWD + col])     = v;
    }
    __syncthreads();

    if (active) {
      #pragma unroll 4
      for (int c = 0; c < KC; ++c) {
        const float4 l4 = *(const float4*)(&Ls[c * NWD + w0]);
        const float4 ra = *(const float4*)(&Rs[c * RST + X0]);      // padded x: X0..X0+3
        const float4 rb = *(const float4*)(&Rs[c * RST + X0 + 4]);  // padded x: X0+4..X0+7
        const float lw[4] = {l4.x, l4.y, l4.z, l4.w};
        const float rw[8] = {ra.x, ra.y, ra.z, ra.w, rb.x, rb.y, rb.z, rb.w};
        // R[w-d] lives at padded index X0 + 4 + (wi - di)  ->  rw[4 + wi - di]
        #pragma unroll
        for (int di = 0; di < 4; ++di)
          #pragma unroll
          for (int wi = 0; wi < 4; ++wi)
            acc[di][wi] = __builtin_fmaf(lw[wi], rw[4 + wi - di], acc[di][wi]);
      }
    }
  }

  if (active) {
    #pragma unroll
    for (int di = 0; di < 4; ++di) {
      const int d = d0 + di;
      #pragma unroll
      for (int wi = 0; wi < 4; ++wi) {
        const int w = w0 + wi;
        if (w >= d)  // garbage (pad reads) only ever landed in w<d accs
          out[(((size_t)b * ND + d) * NH + h) * NWD + w] = acc[di][wi] * 0.00390625f;
      }
    }
  }
}

extern "C" void kernel_launch(void* const* d_in, const int* in_sizes, int n_in,
                              void* d_out, int out_size, void* d_ws, size_t ws_size,
                              hipStream_t stream) {
  corr_valu<<<dim3(NB * NH), dim3(320), 0, stream>>>(
      (const float*)d_in[0], (const float*)d_in[1], (float*)d_out);
}

// Round 5
// 169.280 us; speedup vs baseline: 1.0653x; 1.0653x over previous
//
#include <hip/hip_runtime.h>

// DispNetC correlation volume: out[b,d,h,w] = mean_c L[b,c,h,w]*R[b,c,h,w-d]
// for w>=d, else 0.  f32 in / f32 out.
//
// R4 post-mortem: latency-bound at 2 blocks/CU (10 waves). Fix: split C=256
// into two intra-block teams of 320 threads (640/block), each with private
// KC=16 LDS chunks (33.8 KB/block -> 3 blocks/CU = 30 waves/CU), cross-team
// reduce through LDS at the end. No atomics, deterministic.

#define NB 8
#define NC 256
#define NH 64
#define NWD 128
#define ND 40
#define KC 16
#define LST 132            // padded row stride (floats); 132 mod 32 = 4 bank rotation
#define TEAM_F (2 * KC * LST)  // floats per team (Ls + Rs) = 4224

__global__ __launch_bounds__(640) void corr_valu2(
    const float* __restrict__ Lg,
    const float* __restrict__ Rg,
    float* __restrict__ out)
{
  __shared__ __align__(16) float smem[2 * TEAM_F];  // 33792 B

  const int blk  = blockIdx.x;
  const int b    = blk >> 6;        // NH = 64
  const int h    = blk & 63;
  const int tid  = threadIdx.x;
  const int team = (tid >= 320);
  const int ttid = tid - (team ? 320 : 0);  // 0..319 within team
  const int dt   = ttid >> 5;       // 0..9
  const int wt   = ttid & 31;       // 0..31
  const int d0   = dt << 2;
  const int w0   = wt << 2;
  const bool active = (w0 >= d0);

  float* Ls = smem + team * TEAM_F;          // [KC][LST]
  float* Rs = Ls + KC * LST;                 // [KC][LST], data at col 4+x

  // Zero the w < d triangle (d_out is poisoned before each timed launch).
  for (int t = tid; t < ND * ND; t += 640) {
    const int d = t / ND;
    const int w = t - d * ND;
    if (w < d)
      out[(((size_t)b * ND + d) * NH + h) * NWD + w] = 0.0f;
  }

  float acc[4][4] = {{0.f}};

  const size_t HW   = (size_t)NH * NWD;
  const size_t base = (size_t)b * NC * HW + (size_t)h * NWD
                    + (size_t)(team ? NC / 2 : 0) * HW;  // team's channel base
  const int    X0   = w0 - d0;  // >= 0 for active threads, multiple of 4

  for (int kc = 0; kc < NC / 2; kc += KC) {   // 8 chunks of 16 channels per team
    __syncthreads();  // previous chunk's compute done reading LDS (both teams)
    // ---- stage KC channels of L and R for this team (coalesced float4) ----
    for (int idx = ttid; idx < 2 * KC * 32; idx += 320) {
      const int which = (idx >= KC * 32);            // 0 = L, 1 = R
      const int r     = (idx & (KC * 32 - 1)) >> 5;  // channel row 0..KC-1
      const int col   = (idx & 31) << 2;             // w offset 0..124
      const float* src = which ? Rg : Lg;
      const float4 v = *(const float4*)(src + base + (size_t)(kc + r) * HW + col);
      if (which) *(float4*)(&Rs[r * LST + 4 + col]) = v;  // pad[0..3] stays garbage
      else       *(float4*)(&Ls[r * LST + col])     = v;
    }
    __syncthreads();

    if (active) {
      #pragma unroll 4
      for (int c = 0; c < KC; ++c) {
        const float4 l4 = *(const float4*)(&Ls[c * LST + w0]);
        const float4 ra = *(const float4*)(&Rs[c * LST + X0]);      // R[X0-4..X0-1]
        const float4 rb = *(const float4*)(&Rs[c * LST + X0 + 4]);  // R[X0..X0+3]
        const float lw[4] = {l4.x, l4.y, l4.z, l4.w};
        const float rw[8] = {ra.x, ra.y, ra.z, ra.w, rb.x, rb.y, rb.z, rb.w};
        // R[w-d] = rw[4 + wi - di]; garbage pad only feeds w<d accs (never stored)
        #pragma unroll
        for (int di = 0; di < 4; ++di)
          #pragma unroll
          for (int wi = 0; wi < 4; ++wi)
            acc[di][wi] = __builtin_fmaf(lw[wi], rw[4 + wi - di], acc[di][wi]);
      }
    }
  }

  // ---- cross-team reduce through LDS (smem reused; 320*16 = 5120 floats) ----
  __syncthreads();  // last chunk's compute done before overwrite
  if (team) {
    #pragma unroll
    for (int di = 0; di < 4; ++di)
      #pragma unroll
      for (int wi = 0; wi < 4; ++wi)
        smem[ttid * 16 + di * 4 + wi] = acc[di][wi];
  }
  __syncthreads();
  if (!team) {
    #pragma unroll
    for (int di = 0; di < 4; ++di) {
      const int d = d0 + di;
      #pragma unroll
      for (int wi = 0; wi < 4; ++wi) {
        const int w = w0 + wi;
        if (w >= d) {
          const float s = acc[di][wi] + smem[ttid * 16 + di * 4 + wi];
          out[(((size_t)b * ND + d) * NH + h) * NWD + w] = s * 0.00390625f;  // /256
        }
      }
    }
  }
}

extern "C" void kernel_launch(void* const* d_in, const int* in_sizes, int n_in,
                              void* d_out, int out_size, void* d_ws, size_t ws_size,
                              hipStream_t stream) {
  corr_valu2<<<dim3(NB * NH), dim3(640), 0, stream>>>(
      (const float*)d_in[0], (const float*)d_in[1], (float*)d_out);
}

// Round 6
// 154.459 us; speedup vs baseline: 1.1675x; 1.0960x over previous
//
#include <hip/hip_runtime.h>

// DispNetC correlation volume: out[b,d,h,w] = mean_c L[b,c,h,w]*R[b,c,h,w-d]
// for w>=d, else 0.  f32 in / f32 out (established R1/R4).
//
// Band-matmul via MFMA: per (b,h), G[w',w] = sum_c R[c,w']*L[c,w] (bf16-cast
// inputs, f32 accumulate); out[d,w] = G[w-d,w]. Only the 26 16x16 tiles with
// 0 <= jtile-itile <= 3 intersect the d-band [0,40). This cuts LDS traffic
// ~9x vs the R5 VALU kernel (which was LDS-pipe-bound at ~80%).

typedef __attribute__((ext_vector_type(8))) short short8;   // MFMA A/B frag (8 bf16)
typedef __attribute__((ext_vector_type(4))) float floatx4;  // MFMA C/D frag

#define NB 8
#define NC 256
#define NH 64
#define NWD 128
#define ND 40
#define KC 64   // channels staged per chunk

__global__ __launch_bounds__(256, 2) void corr_mfma(
    const float* __restrict__ Lg,
    const float* __restrict__ Rg,
    float* __restrict__ out)
{
  // [w][c-chunk] bf16, XOR-swizzled 8-c groups for conflict-free b128 r/w.
  __shared__ __align__(16) unsigned short Ls[NWD * KC];  // 16 KB
  __shared__ __align__(16) unsigned short Rs[NWD * KC];  // 16 KB

  const int blk  = blockIdx.x;
  const int b    = blk >> 6;      // NH = 64
  const int h    = blk & 63;
  const int tid  = threadIdx.x;
  const int lane = tid & 63;
  const int wave = tid >> 6;
  const int m    = lane & 15;     // row (A) / col (B,D) within tile
  const int q    = lane >> 4;     // quad

  // Zero the w < d triangle (d_out is poisoned before each timed launch).
  for (int t = tid; t < ND * ND; t += 256) {
    const int d = t / ND;
    const int w = t - d * ND;
    if (w < d)
      out[(((size_t)b * ND + d) * NH + h) * NWD + w] = 0.0f;
  }

  floatx4 acc[7];
  #pragma unroll
  for (int t = 0; t < 7; ++t) acc[t] = (floatx4){0.f, 0.f, 0.f, 0.f};

  const int ws = tid & 127;        // lane -> w for staging (coalesced)
  const int ch = tid >> 7;         // which 8-c slot this thread stages
  const size_t HW   = (size_t)NH * NWD;
  const size_t goff = (size_t)b * NC * HW + (size_t)h * NWD + ws;

  for (int kc = 0; kc < NC; kc += KC) {
    __syncthreads();  // previous chunk's compute done reading LDS
    // ---- stage KC channels: f32 load, round-to-bf16 (+0x8000 half-up), pack ----
    #pragma unroll
    for (int it = 0; it < 4; ++it) {
      const int c0   = kc + it * 16 + ch * 8;
      const size_t g = goff + (size_t)c0 * HW;
      unsigned int lv[4], rv[4];
      #pragma unroll
      for (int p = 0; p < 4; ++p) {
        const unsigned int a0 = __float_as_uint(Lg[g + (size_t)(2 * p) * HW]) + 0x8000u;
        const unsigned int a1 = __float_as_uint(Lg[g + (size_t)(2 * p + 1) * HW]) + 0x8000u;
        lv[p] = (a0 >> 16) | (a1 & 0xFFFF0000u);
        const unsigned int b0 = __float_as_uint(Rg[g + (size_t)(2 * p) * HW]) + 0x8000u;
        const unsigned int b1 = __float_as_uint(Rg[g + (size_t)(2 * p + 1) * HW]) + 0x8000u;
        rv[p] = (b0 >> 16) | (b1 & 0xFFFF0000u);
      }
      const int grp = it * 2 + ch;                        // 8-c group in chunk, 0..7
      const int pos = ws * KC + ((grp ^ (ws & 7)) << 3);  // XOR swizzle
      *(uint4*)(&Ls[pos]) = make_uint4(lv[0], lv[1], lv[2], lv[3]);
      *(uint4*)(&Rs[pos]) = make_uint4(rv[0], rv[1], rv[2], rv[3]);
    }
    __syncthreads();

    // ---- band tiles: (i, j=i+k), k=0..3; 26 tiles round-robined over 4 waves ----
    #pragma unroll
    for (int ks = 0; ks < 2; ++ks) {       // two K=32 steps per 64-c chunk
      #pragma unroll
      for (int tile = 0; tile < 26; ++tile) {
        if ((tile & 3) != wave) continue;
        const int i  = (tile < 8) ? tile : (tile < 15) ? tile - 8
                     : (tile < 21) ? tile - 15 : tile - 21;
        const int k  = (tile < 8) ? 0 : (tile < 15) ? 1 : (tile < 21) ? 2 : 3;
        const int j  = i + k;
        const int tt = tile >> 2;
        const int ra = 16 * i + m;         // w' row for A (from R)
        const int rb = 16 * j + m;         // w  col for B (from L)
        const int grp = ks * 4 + q;        // lane reads c = 32*ks + 8*q + [0..7]
        const short8 av = *(const short8*)(&Rs[ra * KC + ((grp ^ (ra & 7)) << 3)]);
        const short8 bv = *(const short8*)(&Ls[rb * KC + ((grp ^ (rb & 7)) << 3)]);
        acc[tt] = __builtin_amdgcn_mfma_f32_16x16x32_bf16(av, bv, acc[tt], 0, 0, 0);
      }
    }
  }

  // Epilogue: D layout col=lane&15 (w in tile j), row=q*4+reg (w' in tile i).
  #pragma unroll
  for (int tile = 0; tile < 26; ++tile) {
    if ((tile & 3) != wave) continue;
    const int i  = (tile < 8) ? tile : (tile < 15) ? tile - 8
                 : (tile < 21) ? tile - 15 : tile - 21;
    const int k  = (tile < 8) ? 0 : (tile < 15) ? 1 : (tile < 21) ? 2 : 3;
    const int j  = i + k;
    const int tt = tile >> 2;
    const int w  = 16 * j + m;
    #pragma unroll
    for (int r = 0; r < 4; ++r) {
      const int wp = 16 * i + q * 4 + r;
      const int d  = w - wp;
      if (d >= 0 && d < ND)
        out[(((size_t)b * ND + d) * NH + h) * NWD + w] = acc[tt][r] * 0.00390625f;
    }
  }
}

extern "C" void kernel_launch(void* const* d_in, const int* in_sizes, int n_in,
                              void* d_out, int out_size, void* d_ws, size_t ws_size,
                              hipStream_t stream) {
  corr_mfma<<<dim3(NB * NH), dim3(256), 0, stream>>>(
      (const float*)d_in[0], (const float*)d_in[1], (float*)d_out);
}

// Round 7
// 151.430 us; speedup vs baseline: 1.1909x; 1.0200x over previous
//
#include <hip/hip_runtime.h>

// DispNetC correlation volume: out[b,d,h,w] = mean_c L[b,c,h,w]*R[b,c,h,w-d]
// for w>=d, else 0.  f32 in / f32 out.
//
// Band-matmul via MFMA (R6 structure, hardware-verified absmax 2e-3), now with
// C=256 split over 4 intra-block teams (1024 thr, 128 KB LDS, 1 block/CU):
// one staging round instead of a 4-round barrier'd K-loop (R6 was latency-
// bound at 17% occupancy, all pipes <25%). f32 partials reduced through LDS.

typedef __attribute__((ext_vector_type(8))) short short8;   // MFMA A/B frag
typedef __attribute__((ext_vector_type(4))) float floatx4;  // MFMA C/D frag

#define NB 8
#define NC 256
#define NH 64
#define NWD 128
#define ND 40
#define KC 64                            // channels per team
#define TEAM_BYTES (2 * NWD * KC * 2)    // Ls+Rs (bf16) = 32 KB per team

__global__ __launch_bounds__(1024, 4) void corr_mfma4(
    const float* __restrict__ Lg,
    const float* __restrict__ Rg,
    float* __restrict__ out)
{
  __shared__ __align__(16) unsigned char smem[4 * TEAM_BYTES];  // 128 KB

  const int blk  = blockIdx.x;
  const int b    = blk >> 6;      // NH = 64
  const int h    = blk & 63;
  const int tid  = threadIdx.x;
  const int team = tid >> 8;      // 0..3: which 64-channel quarter
  const int ttid = tid & 255;
  const int lane = tid & 63;
  const int wavt = (tid >> 6) & 3;  // wave within team
  const int m    = lane & 15;
  const int q    = lane >> 4;

  unsigned short* Ls = (unsigned short*)(smem + team * TEAM_BYTES);
  unsigned short* Rs = Ls + NWD * KC;

  // ---- stage this team's 64 channels: f32 load, round-half-up bf16, pack ----
  // [w][c] layout, XOR-swizzled 8-c groups (R6-verified: 0 bank conflicts).
  const int ws = ttid & 127;
  const int ch = ttid >> 7;
  const size_t HW   = (size_t)NH * NWD;
  const size_t goff = (size_t)b * NC * HW + (size_t)h * NWD
                    + (size_t)(team * KC) * HW + ws;
  #pragma unroll
  for (int it = 0; it < 4; ++it) {
    const size_t g = goff + (size_t)(it * 16 + ch * 8) * HW;
    unsigned int lv[4], rv[4];
    #pragma unroll
    for (int p = 0; p < 4; ++p) {
      const unsigned int a0 = __float_as_uint(Lg[g + (size_t)(2 * p) * HW]) + 0x8000u;
      const unsigned int a1 = __float_as_uint(Lg[g + (size_t)(2 * p + 1) * HW]) + 0x8000u;
      lv[p] = (a0 >> 16) | (a1 & 0xFFFF0000u);
      const unsigned int b0 = __float_as_uint(Rg[g + (size_t)(2 * p) * HW]) + 0x8000u;
      const unsigned int b1 = __float_as_uint(Rg[g + (size_t)(2 * p + 1) * HW]) + 0x8000u;
      rv[p] = (b0 >> 16) | (b1 & 0xFFFF0000u);
    }
    const int grp = it * 2 + ch;                        // 8-c group, 0..7
    const int pos = ws * KC + ((grp ^ (ws & 7)) << 3);  // XOR swizzle
    *(uint4*)(&Ls[pos]) = make_uint4(lv[0], lv[1], lv[2], lv[3]);
    *(uint4*)(&Rs[pos]) = make_uint4(rv[0], rv[1], rv[2], rv[3]);
  }
  __syncthreads();

  // ---- band tiles (i, j=i+k), k=0..3; 26 tiles round-robined over 4 waves ----
  floatx4 acc[7];
  #pragma unroll
  for (int t = 0; t < 7; ++t) acc[t] = (floatx4){0.f, 0.f, 0.f, 0.f};
  #pragma unroll
  for (int ks = 0; ks < 2; ++ks) {       // two K=32 steps over the 64 channels
    #pragma unroll
    for (int tile = 0; tile < 26; ++tile) {
      if ((tile & 3) != wavt) continue;
      const int i  = (tile < 8) ? tile : (tile < 15) ? tile - 8
                   : (tile < 21) ? tile - 15 : tile - 21;
      const int k  = (tile < 8) ? 0 : (tile < 15) ? 1 : (tile < 21) ? 2 : 3;
      const int j  = i + k;
      const int tt = tile >> 2;
      const int ra = 16 * i + m;         // w' row for A (from R)
      const int rb = 16 * j + m;         // w  col for B (from L)
      const int grp = ks * 4 + q;        // lane reads c = 32*ks + 8*q + [0..7]
      const short8 av = *(const short8*)(&Rs[ra * KC + ((grp ^ (ra & 7)) << 3)]);
      const short8 bv = *(const short8*)(&Ls[rb * KC + ((grp ^ (rb & 7)) << 3)]);
      acc[tt] = __builtin_amdgcn_mfma_f32_16x16x32_bf16(av, bv, acc[tt], 0, 0, 0);
    }
  }
  __syncthreads();  // all teams done reading staged LDS

  // ---- dump partial tiles (f32) into own team's region ----
  // index: tile*256 + wp_local*16 + w_local  (D layout: row=q*4+r, col=m)
  float* P = (float*)(smem + team * TEAM_BYTES);
  #pragma unroll
  for (int tile = 0; tile < 26; ++tile) {
    if ((tile & 3) != wavt) continue;
    const int tt = tile >> 2;
    #pragma unroll
    for (int r = 0; r < 4; ++r)
      P[tile * 256 + (q * 4 + r) * 16 + m] = acc[tt][r];
  }
  __syncthreads();

  // ---- reduce the 4 team partials and store (also zero-fills w<d) ----
  for (int t = tid; t < ND * NWD; t += 1024) {
    const int d = t >> 7;
    const int w = t & 127;
    float v = 0.0f;
    if (w >= d) {
      const int wp  = w - d;
      const int i   = wp >> 4;
      const int k   = (w >> 4) - i;
      const int off = (k == 0) ? 0 : (k == 1) ? 8 : (k == 2) ? 15 : 21;
      const int idx = (off + i) * 256 + (wp & 15) * 16 + (w & 15);
      v = (((const float*)(smem + 0 * TEAM_BYTES))[idx] +
           ((const float*)(smem + 1 * TEAM_BYTES))[idx]) +
          (((const float*)(smem + 2 * TEAM_BYTES))[idx] +
           ((const float*)(smem + 3 * TEAM_BYTES))[idx]);
      v *= 0.00390625f;  // /256 (mean over C)
    }
    out[(((size_t)b * ND + d) * NH + h) * NWD + w] = v;
  }
}

extern "C" void kernel_launch(void* const* d_in, const int* in_sizes, int n_in,
                              void* d_out, int out_size, void* d_ws, size_t ws_size,
                              hipStream_t stream) {
  corr_mfma4<<<dim3(NB * NH), dim3(1024), 0, stream>>>(
      (const float*)d_in[0], (const float*)d_in[1], (float*)d_out);
}